// Round 2
// baseline (872.545 us; speedup 1.0000x reference)
//
#include <hip/hip_runtime.h>
#include <math.h>

// STFT via per-frame radix-2 DIT FFT in LDS, with f64 basis-row fixup for
// bins near the atan2 branch cut (|re| or |im| < TAU) so the sign of imag
// matches the f64 numpy reference (which convolves with the fp32 basis).
// x: (32, 1, 262144) fp32; basis: (1026, 1, 1024) fp32 (real rows 0..512,
// imag rows 513..1025). out: mag (32,513,1029) ++ angle (32,513,1029), fp32.

#define NFFT     1024
#define LOG2N    10
#define STRIDE_  256
#define CUTOFF_  513
#define NFRAMES  1029
#define BATCH_   32
#define XLEN     262144
#define FB       8            // frames per block
#define TPB      256
#define NTILES   129          // ceil(1029/8)
#define RSTRIDE  (FB + 1)     // 9 (odd) -> conflict-free result buffer
#define QCAP     1024         // fixup worklist capacity (expected ~19/block)
#define TAU      0.05f

__global__ __launch_bounds__(TPB) void stft_fft_kernel(
    const float* __restrict__ x, const float* __restrict__ basis,
    float* __restrict__ out)
{
    __shared__ float2 a[NFFT];                 // 8 KB FFT workspace
    __shared__ float resM[CUTOFF_ * RSTRIDE];  // 18.5 KB
    __shared__ float resA[CUTOFF_ * RSTRIDE];  // 18.5 KB
    __shared__ unsigned int queue[QCAP];       // 4 KB fixup worklist
    __shared__ int qn;

    const int tid  = threadIdx.x;
    const int bx   = blockIdx.x;
    const int n    = bx / NTILES;
    const int tile = bx % NTILES;
    const int t0   = tile * FB;
    const int nt   = min(FB, NFRAMES - t0);

    const float* __restrict__ xb = x + (size_t)n * XLEN;
    const float TWO_PI = 6.28318530717958647692f;

    if (tid == 0) qn = 0;
    __syncthreads();

    for (int ft = 0; ft < nt; ++ft) {
        const int t    = t0 + ft;
        const int base = t * STRIDE_ - NFFT;

        // ---- load + Hann window, store bit-reversed ----
        #pragma unroll
        for (int k = 0; k < NFFT / TPB; ++k) {
            int i = tid + k * TPB;
            int p = base + i;
            float v = (p >= 0 && p < XLEN) ? xb[p] : 0.0f;
            float w = 0.5f - 0.5f * __cosf(TWO_PI * (float)i * (1.0f / NFFT));
            int r = __brev((unsigned)i) >> (32 - LOG2N);
            a[r] = make_float2(v * w, 0.0f);
        }
        __syncthreads();

        // ---- 10 radix-2 DIT stages ----
        for (int s = 1; s <= LOG2N; ++s) {
            const int half = 1 << (s - 1);
            #pragma unroll
            for (int q = 0; q < (NFFT / 2) / TPB; ++q) {
                int idx = tid + q * TPB;
                int j   = idx & (half - 1);
                int g   = idx >> (s - 1);
                int p1  = (g << s) + j;
                int p2  = p1 + half;
                float ang = -TWO_PI * (float)j / (float)(1 << s);
                float sn, cs;
                __sincosf(ang, &sn, &cs);
                float2 u = a[p1];
                float2 v = a[p2];
                float tr = cs * v.x - sn * v.y;
                float ti = cs * v.y + sn * v.x;
                a[p1] = make_float2(u.x + tr, u.y + ti);
                a[p2] = make_float2(u.x - tr, u.y - ti);
            }
            __syncthreads();
        }

        // ---- epilogue: mag/angle; queue branch-cut-risk bins for f64 fixup
        for (int f = tid; f < CUTOFF_; f += TPB) {
            float2 z = a[f];
            resM[f * RSTRIDE + ft] = sqrtf(z.x * z.x + z.y * z.y);
            resA[f * RSTRIDE + ft] = atan2f(z.y, z.x);
            if (fabsf(z.y) < TAU || fabsf(z.x) < TAU) {
                int qi = atomicAdd(&qn, 1);
                if (qi < QCAP)
                    queue[qi] = ((unsigned)ft << 16) | (unsigned)f;
            }
        }
        __syncthreads();   // a[] reused by next frame's load
    }

    // ---- f64 fixup: wave-cooperative dot with the ACTUAL fp32 basis rows,
    //      accumulated in f64 -> matches the numpy f64 reference's imag sign
    //      even where the basis rows are ~1e-16 noise (bins 0, 512).
    {
        const int nq   = min(qn, QCAP);
        const int wave = tid >> 6;
        const int lane = tid & 63;
        for (int qi = wave; qi < nq; qi += TPB / 64) {
            unsigned e = queue[qi];
            int f  = (int)(e & 0xffffu);
            int ft = (int)(e >> 16);
            int base = (t0 + ft) * STRIDE_ - NFFT;
            const float* __restrict__ br = basis + (size_t)f * NFFT;
            const float* __restrict__ bi = basis + (size_t)(CUTOFF_ + f) * NFFT;
            double sr = 0.0, si = 0.0;
            for (int h = lane; h < NFFT; h += 64) {
                int p = base + h;
                if (p >= 0 && p < XLEN) {
                    double xv = (double)xb[p];
                    sr += xv * (double)br[h];
                    si += xv * (double)bi[h];
                }
            }
            #pragma unroll
            for (int off = 32; off; off >>= 1) {
                sr += __shfl_down(sr, off);
                si += __shfl_down(si, off);
            }
            if (lane == 0) {
                float re = (float)sr, im = (float)si;
                resM[f * RSTRIDE + ft] = sqrtf(re * re + im * im);
                resA[f * RSTRIDE + ft] = atan2f(im, re);
            }
        }
    }
    __syncthreads();

    // ---- coalesced write-out: per frequency row, nt consecutive t ----
    const size_t magbase = (size_t)n * CUTOFF_ * NFRAMES;
    const size_t angoff  = (size_t)BATCH_ * CUTOFF_ * NFRAMES;
    for (int idx = tid; idx < CUTOFF_ * FB; idx += TPB) {
        int f  = idx >> 3;        // idx / FB
        int tt = idx & (FB - 1);  // idx % FB
        if (tt < nt) {
            size_t o = magbase + (size_t)f * NFRAMES + (size_t)(t0 + tt);
            out[o]          = resM[f * RSTRIDE + tt];
            out[angoff + o] = resA[f * RSTRIDE + tt];
        }
    }
}

extern "C" void kernel_launch(void* const* d_in, const int* in_sizes, int n_in,
                              void* d_out, int out_size, void* d_ws, size_t ws_size,
                              hipStream_t stream) {
    const float* x     = (const float*)d_in[0];
    const float* basis = (const float*)d_in[1];
    float* out = (float*)d_out;
    dim3 grid(BATCH_ * NTILES);
    dim3 block(TPB);
    stft_fft_kernel<<<grid, block, 0, stream>>>(x, basis, out);
}